// Round 10
// baseline (11274.565 us; speedup 1.0000x reference)
//
#include <hip/hip_runtime.h>
#include <cmath>

#define B 64
#define S 4096
#define NI 16
#define H 128
#define F 144   // H + NI
#define CH 16   // timesteps per chunk
#define NCH (S / CH)

typedef _Float16 h2   __attribute__((ext_vector_type(2)));
typedef _Float16 h4v  __attribute__((ext_vector_type(4)));
typedef _Float16 h8   __attribute__((ext_vector_type(8)));
typedef float    f4v  __attribute__((ext_vector_type(4)));

__device__ __forceinline__ float rcp_fast(float x) { return __builtin_amdgcn_rcpf(x); }
__device__ __forceinline__ float sigf(float x) {
    return rcp_fast(1.0f + __expf(-x));
}
// tanh(x) = 2*sigmoid(2x) - 1
__device__ __forceinline__ float tanh_fast(float x) {
    const float e = __expf(-2.0f * x);
    return fmaf(2.0f, rcp_fast(1.0f + e), -1.0f);
}
// all 4 lanes of each quad end with the 4-lane sum
__device__ __forceinline__ float quad_reduce(float v) {
    int t1 = __builtin_amdgcn_mov_dpp(__float_as_int(v), 0xB1, 0xf, 0xf, true); // xor 1
    v += __int_as_float(t1);
    int t2 = __builtin_amdgcn_mov_dpp(__float_as_int(v), 0x4E, 0xf, 0xf, true); // xor 2
    v += __int_as_float(t2);
    return v;
}
// both lanes of each pair end with the 2-lane sum
__device__ __forceinline__ float pair_reduce(float v) {
    int t1 = __builtin_amdgcn_mov_dpp(__float_as_int(v), 0xB1, 0xf, 0xf, true); // xor 1
    v += __int_as_float(t1);
    return v;
}
__device__ __forceinline__ h2 cvt2(float a, float b) {
    h2 r; r[0] = (_Float16)a; r[1] = (_Float16)b; return r;
}
__device__ __forceinline__ void cvt8(const float* p, h2* w) {
    const float4 f0 = ((const float4*)p)[0];
    const float4 f1 = ((const float4*)p)[1];
    w[0] = cvt2(f0.x, f0.y); w[1] = cvt2(f0.z, f0.w);
    w[2] = cvt2(f1.x, f1.y); w[3] = cvt2(f1.z, f1.w);
}
__device__ __forceinline__ h8 cvt8v(const float* p) {
    const float4 f0 = ((const float4*)p)[0];
    const float4 f1 = ((const float4*)p)[1];
    h8 r;
    r[0] = (_Float16)f0.x; r[1] = (_Float16)f0.y;
    r[2] = (_Float16)f0.z; r[3] = (_Float16)f0.w;
    r[4] = (_Float16)f1.x; r[5] = (_Float16)f1.y;
    r[6] = (_Float16)f1.z; r[7] = (_Float16)f1.w;
    return r;
}
__device__ __forceinline__ void pin_h2(h2& v) {
    int t = __builtin_bit_cast(int, v);
    asm volatile("" : "+v"(t));
    v = __builtin_bit_cast(h2, t);
}
__device__ __forceinline__ void pin_f(float& v) {
    asm volatile("" : "+v"(v));
}
__device__ __forceinline__ f4v mfma16(h8 a, h8 b, f4v c) {
    return __builtin_amdgcn_mfma_f32_16x16x32_f16(a, b, c, 0, 0, 0);
}

// ---------------------------------------------------------------------------
// Fused 2-layer GRU with MFMA-precomputed gi1.
// 64 blocks x 768 threads (12 waves, 3/SIMD).
//  waves 0-3 (tid<256): L0 pair-split (j=tid>>1, m=tid&1 owns 64 h-cols + 8
//     x-cols). Writes h0 state (sH0 ping-pong) AND banks h0 into sH0c chunks.
//  waves 4-11 (tid>=256): L1.
//     - every 16 iters: chunk-GEMM gi1[c] = W_ih1 (384x128) x h0c (16x128)^T
//       via 12 mfma_16x16x32 per wave (A=W rows [stationary frags], B=h0
//       rows, D[gate,t] -> sGi). Same verified layout as head_mfma.
//     - per step (lag 17): only the recurrent half gh1 = W_hh1 . h1[t-1]
//       (quad-split, 48 fdot2) + gi1 read from sGi + activation.
// h1 stored fp16 to global per chunk for the MFMA head.
// ---------------------------------------------------------------------------
__global__ __launch_bounds__(768, 3)
void gru_fused(const float* __restrict__ x,
               const float* __restrict__ w_ih0, const float* __restrict__ w_hh0,
               const float* __restrict__ b_ih0, const float* __restrict__ b_hh0,
               const float* __restrict__ w_ih1, const float* __restrict__ w_hh1,
               const float* __restrict__ b_ih1, const float* __restrict__ b_hh1,
               _Float16* __restrict__ h_out)
{
    __shared__ __align__(16) _Float16 sH0[2][H];        // h0 state ping-pong
    __shared__ __align__(16) _Float16 sH1[2][H];        // h1 state ping-pong
    __shared__ __align__(16) _Float16 sX[2][CH][NI];    // x chunks (fp16)
    __shared__ __align__(16) _Float16 sH0c[2][CH][136]; // h0 chunk bank (pad 136)
    __shared__ __align__(16) float    sGi[2][CH][396];  // gi1 chunks (pad 396)
    __shared__ __align__(16) _Float16 sHo[2][CH][H];    // h1 out accum (fp16)

    const int b    = blockIdx.x;
    const int tid  = threadIdx.x;
    const bool isL0 = (tid < 256);

    h2 wreg[96];          // L0: 3x32 h2 (hh). L1: 3x16 h2 (hh) in [0..47]
    h2 wx[12];            // L0 only
    h8 Af[3][4];          // L1 only: stationary W_ih1 A-fragments
    float b_r, b_z, b_in, b_hn;
    int j, m, nl, q2, wave1;

    if (isL0) {
        j = tid >> 1; m = tid & 1;
        nl = 0; q2 = 0; wave1 = 0;
#pragma unroll
        for (int ii = 0; ii < 8; ii++) {
            cvt8(w_hh0 + (size_t)j * H         + 64 * m + 8 * ii, &wreg[4 * ii]);
            cvt8(w_hh0 + (size_t)(H + j) * H   + 64 * m + 8 * ii, &wreg[32 + 4 * ii]);
            cvt8(w_hh0 + (size_t)(2*H + j) * H + 64 * m + 8 * ii, &wreg[64 + 4 * ii]);
        }
        cvt8(w_ih0 + (size_t)j * NI         + 8 * m, &wx[0]);
        cvt8(w_ih0 + (size_t)(H + j) * NI   + 8 * m, &wx[4]);
        cvt8(w_ih0 + (size_t)(2*H + j) * NI + 8 * m, &wx[8]);
        b_r  = b_ih0[j]       + b_hh0[j];
        b_z  = b_ih0[H + j]   + b_hh0[H + j];
        b_in = b_ih0[2*H + j];
        b_hn = b_hh0[2*H + j];
#pragma unroll
        for (int i = 0; i < 96; i++) pin_h2(wreg[i]);
#pragma unroll
        for (int i = 0; i < 12; i++) pin_h2(wx[i]);
    } else {
        const int tid1 = tid - 256;
        j = tid1 >> 2; m = tid1 & 3;
        const int lane = tid1 & 63;
        nl = lane & 15; q2 = lane >> 4;
        wave1 = tid1 >> 6;                         // 0..7
        // gh weights, quad-split, load-permuted: slot i = sub-chunk (i+m)&3
#pragma unroll
        for (int i = 0; i < 4; i++) {
            const int f = (i + m) & 3;
            const int o = 32 * m + 8 * f;
            cvt8(w_hh1 + (size_t)j * H         + o, &wreg[ 0 + 4 * i]);
            cvt8(w_hh1 + (size_t)(H + j) * H   + o, &wreg[16 + 4 * i]);
            cvt8(w_hh1 + (size_t)(2*H + j) * H + o, &wreg[32 + 4 * i]);
        }
        // stationary A-fragments of W_ih1: wave handles m-tiles 3w..3w+2
#pragma unroll
        for (int tt = 0; tt < 3; tt++) {
            const float* wr = w_ih1 + (size_t)((3 * wave1 + tt) * 16 + nl) * H;
#pragma unroll
            for (int cc = 0; cc < 4; cc++)
                Af[tt][cc] = cvt8v(wr + 32 * cc + 8 * q2);
        }
        b_r  = b_ih1[j]       + b_hh1[j];
        b_z  = b_ih1[H + j]   + b_hh1[H + j];
        b_in = b_ih1[2*H + j];
        b_hn = b_hh1[2*H + j];
#pragma unroll
        for (int i = 0; i < 48; i++) pin_h2(wreg[i]);
    }
    pin_f(b_r); pin_f(b_z); pin_f(b_in); pin_f(b_hn);

    const float* xb = x + (size_t)b * S * NI;
    _Float16*    hb = h_out + (size_t)b * S * H;

    float4 xreg = {0.f, 0.f, 0.f, 0.f};
    if (tid < H) { sH0[0][tid] = (_Float16)0.0f; sH1[1][tid] = (_Float16)0.0f; }
    if (tid < 64) {
        const float4 v = ((const float4*)xb)[tid];
        h4v p; p[0] = (_Float16)v.x; p[1] = (_Float16)v.y;
               p[2] = (_Float16)v.z; p[3] = (_Float16)v.w;
        ((h4v*)&sX[0][0][0])[tid] = p;
        xreg = ((const float4*)(xb + CH * NI))[tid];
    }
    float hprev = 0.0f;
    __syncthreads();

    for (int k = 0; k < S + 17; k++) {
        const int cur = k & 1;

        if (isL0) {
            if (k < S) {
                const int c0  = k >> 4;
                const int tw0 = k & (CH - 1);

                if (tw0 == 0 && tid < 64) {
                    const int cn = c0 + 1;
                    if (cn < NCH) {
                        h4v p; p[0] = (_Float16)xreg.x; p[1] = (_Float16)xreg.y;
                               p[2] = (_Float16)xreg.z; p[3] = (_Float16)xreg.w;
                        ((h4v*)&sX[cn & 1][0][0])[tid] = p;
                        if (cn + 1 < NCH)
                            xreg = ((const float4*)(xb + (size_t)(cn + 1) * CH * NI))[tid];
                    }
                }

                const float4* hv = (const float4*)&sH0[cur][0];
                float ar = 0.f, az = 0.f, ahn = 0.f;
#pragma unroll
                for (int i = 0; i < 8; i++) {
                    const float4 q = hv[8 * m + i];
                    const h2 p0 = __builtin_bit_cast(h2, q.x);
                    const h2 p1 = __builtin_bit_cast(h2, q.y);
                    const h2 p2 = __builtin_bit_cast(h2, q.z);
                    const h2 p3 = __builtin_bit_cast(h2, q.w);
                    ar  = __builtin_amdgcn_fdot2(p0, wreg[4*i+0],    ar,  false);
                    ar  = __builtin_amdgcn_fdot2(p1, wreg[4*i+1],    ar,  false);
                    ar  = __builtin_amdgcn_fdot2(p2, wreg[4*i+2],    ar,  false);
                    ar  = __builtin_amdgcn_fdot2(p3, wreg[4*i+3],    ar,  false);
                    az  = __builtin_amdgcn_fdot2(p0, wreg[32+4*i+0], az,  false);
                    az  = __builtin_amdgcn_fdot2(p1, wreg[32+4*i+1], az,  false);
                    az  = __builtin_amdgcn_fdot2(p2, wreg[32+4*i+2], az,  false);
                    az  = __builtin_amdgcn_fdot2(p3, wreg[32+4*i+3], az,  false);
                    ahn = __builtin_amdgcn_fdot2(p0, wreg[64+4*i+0], ahn, false);
                    ahn = __builtin_amdgcn_fdot2(p1, wreg[64+4*i+1], ahn, false);
                    ahn = __builtin_amdgcn_fdot2(p2, wreg[64+4*i+2], ahn, false);
                    ahn = __builtin_amdgcn_fdot2(p3, wreg[64+4*i+3], ahn, false);
                }
                const float4 xq = *(const float4*)&sX[c0 & 1][tw0][8 * m];
                const h2 x0 = __builtin_bit_cast(h2, xq.x);
                const h2 x1 = __builtin_bit_cast(h2, xq.y);
                const h2 x2 = __builtin_bit_cast(h2, xq.z);
                const h2 x3 = __builtin_bit_cast(h2, xq.w);
                float ain = 0.f;
                ar  = __builtin_amdgcn_fdot2(x0, wx[0],  ar,  false);
                ar  = __builtin_amdgcn_fdot2(x1, wx[1],  ar,  false);
                ar  = __builtin_amdgcn_fdot2(x2, wx[2],  ar,  false);
                ar  = __builtin_amdgcn_fdot2(x3, wx[3],  ar,  false);
                az  = __builtin_amdgcn_fdot2(x0, wx[4],  az,  false);
                az  = __builtin_amdgcn_fdot2(x1, wx[5],  az,  false);
                az  = __builtin_amdgcn_fdot2(x2, wx[6],  az,  false);
                az  = __builtin_amdgcn_fdot2(x3, wx[7],  az,  false);
                ain = __builtin_amdgcn_fdot2(x0, wx[8],  ain, false);
                ain = __builtin_amdgcn_fdot2(x1, wx[9],  ain, false);
                ain = __builtin_amdgcn_fdot2(x2, wx[10], ain, false);
                ain = __builtin_amdgcn_fdot2(x3, wx[11], ain, false);

                const float vr  = pair_reduce(ar)  + b_r;
                const float vz  = pair_reduce(az)  + b_z;
                const float vhn = pair_reduce(ahn) + b_hn;
                const float vin = pair_reduce(ain) + b_in;

                const float r  = sigf(vr);
                const float z  = sigf(vz);
                const float n  = tanh_fast(vin + r * vhn);
                const float hn = n + z * (hprev - n);
                hprev = hn;
                if (m == 0) {
                    const _Float16 hf = (_Float16)hn;
                    sH0[cur ^ 1][j]       = hf;
                    sH0c[c0 & 1][tw0][j]  = hf;   // bank for the gi1 GEMM
                }
            }
        } else {
            // ---- chunk GEMM: gi1[c] from banked h0 chunk c = (k>>4)-1 ----
            if ((k & 15) == 0 && k >= 16 && k <= S) {
                const int c   = (k >> 4) - 1;
                const int buf = c & 1;
                const h8 Bc0 = *(const h8*)&sH0c[buf][nl][ 0 + 8 * q2];
                const h8 Bc1 = *(const h8*)&sH0c[buf][nl][32 + 8 * q2];
                const h8 Bc2 = *(const h8*)&sH0c[buf][nl][64 + 8 * q2];
                const h8 Bc3 = *(const h8*)&sH0c[buf][nl][96 + 8 * q2];
#pragma unroll
                for (int tt = 0; tt < 3; tt++) {
                    f4v acc = {0.f, 0.f, 0.f, 0.f};
                    acc = mfma16(Af[tt][0], Bc0, acc);
                    acc = mfma16(Af[tt][1], Bc1, acc);
                    acc = mfma16(Af[tt][2], Bc2, acc);
                    acc = mfma16(Af[tt][3], Bc3, acc);
                    const int g0 = (3 * wave1 + tt) * 16 + 4 * q2;
#pragma unroll
                    for (int r = 0; r < 4; r++)
                        sGi[buf][nl][g0 + r] = acc[r];   // D[gate,t=nl]
                }
            }
            // ---- per-step recurrent half, lag 17: t = k - 17 ----
            if (k >= 17) {
                const int t   = k - 17;
                const int ct  = t >> 4;
                const int twt = t & (CH - 1);

                const float4* C4 = (const float4*)&sH1[cur][0];   // h1[t-1]
                float ar = 0.f, az = 0.f, ahn = 0.f;
#pragma unroll
                for (int i = 0; i < 4; i++) {
                    const int f = (i + m) & 3;                    // addr stagger
                    const float4 qc = C4[4 * m + f];
                    const h2 c0 = __builtin_bit_cast(h2, qc.x);
                    const h2 c1 = __builtin_bit_cast(h2, qc.y);
                    const h2 c2 = __builtin_bit_cast(h2, qc.z);
                    const h2 c3 = __builtin_bit_cast(h2, qc.w);
                    ar  = __builtin_amdgcn_fdot2(c0, wreg[ 0+4*i+0], ar,  false);
                    ar  = __builtin_amdgcn_fdot2(c1, wreg[ 0+4*i+1], ar,  false);
                    ar  = __builtin_amdgcn_fdot2(c2, wreg[ 0+4*i+2], ar,  false);
                    ar  = __builtin_amdgcn_fdot2(c3, wreg[ 0+4*i+3], ar,  false);
                    az  = __builtin_amdgcn_fdot2(c0, wreg[16+4*i+0], az,  false);
                    az  = __builtin_amdgcn_fdot2(c1, wreg[16+4*i+1], az,  false);
                    az  = __builtin_amdgcn_fdot2(c2, wreg[16+4*i+2], az,  false);
                    az  = __builtin_amdgcn_fdot2(c3, wreg[16+4*i+3], az,  false);
                    ahn = __builtin_amdgcn_fdot2(c0, wreg[32+4*i+0], ahn, false);
                    ahn = __builtin_amdgcn_fdot2(c1, wreg[32+4*i+1], ahn, false);
                    ahn = __builtin_amdgcn_fdot2(c2, wreg[32+4*i+2], ahn, false);
                    ahn = __builtin_amdgcn_fdot2(c3, wreg[32+4*i+3], ahn, false);
                }
                const float gr  = quad_reduce(ar);
                const float gz  = quad_reduce(az);
                const float ghn = quad_reduce(ahn);

                const float* gp = &sGi[ct & 1][twt][0];
                const float gi_r = gp[j];
                const float gi_z = gp[128 + j];
                const float gi_n = gp[256 + j];

                const float r  = sigf(gr + gi_r + b_r);
                const float z  = sigf(gz + gi_z + b_z);
                const float n  = tanh_fast(gi_n + b_in + r * (ghn + b_hn));
                const float hn = n + z * (hprev - n);
                hprev = hn;
                if (m == 0) {
                    sH1[cur ^ 1][j]     = (_Float16)hn;
                    sHo[ct & 1][twt][j] = (_Float16)hn;
                }
                // flush completed h1 chunk cp = (k-33)>>4
                if ((k & 15) == 1 && k >= 33) {
                    const int cp  = (k - 33) >> 4;
                    const int idx = tid - 256;
                    const uint2 v = ((const uint2*)&sHo[cp & 1][0][0])[idx];
                    ((uint2*)(hb + (size_t)cp * CH * H))[idx] = v;
                }
            }
        }
        __syncthreads();
    }

    // epilogue: flush last chunk (cp = 255, buffer 1)
    if (!isL0) {
        const int idx = tid - 256;
        const uint2 v = ((const uint2*)&sHo[1][0][0])[idx];
        ((uint2*)(hb + (size_t)(NCH - 1) * CH * H))[idx] = v;
    }
}

// ---------------------------------------------------------------------------
// MFMA MLP head (verified round 9). 512 blocks x 256 threads.
// ---------------------------------------------------------------------------
__global__ __launch_bounds__(256, 2)
void head_mfma(const _Float16* __restrict__ h1, const float* __restrict__ x,
               const float* __restrict__ w1, const float* __restrict__ b1,
               const float* __restrict__ w2, const float* __restrict__ b2,
               float* __restrict__ inc)
{
    const int wave = threadIdx.x >> 6;
    const int lane = threadIdx.x & 63;
    const int nl   = lane & 15;
    const int q    = lane >> 4;

    h8 Bf[4][5];
    float b1v[4], w2v[4];
#pragma unroll
    for (int t = 0; t < 4; t++) {
        const int n = 16 * t + nl;
        const float* wr = w1 + (size_t)n * F;
#pragma unroll
        for (int c = 0; c < 4; c++)
            Bf[t][c] = cvt8v(wr + 32 * c + 8 * q);
        if (q < 2) Bf[t][4] = cvt8v(wr + 128 + 8 * q);
        else { h8 z = {}; Bf[t][4] = z; }
        b1v[t] = b1[n];
        w2v[t] = w2[n];
    }
    const float b2v = b2[0];

    const int gw = blockIdx.x * 4 + wave;

    for (int it = 0; it < 8; it++) {
        const int row0 = (gw * 8 + it) * 16;
        const int rm   = row0 + nl;

        const _Float16* hp = h1 + (size_t)rm * H;
        h8 A0 = *(const h8*)(hp + 8 * q);
        h8 A1 = *(const h8*)(hp + 32 + 8 * q);
        h8 A2 = *(const h8*)(hp + 64 + 8 * q);
        h8 A3 = *(const h8*)(hp + 96 + 8 * q);
        h8 A4;
        if (q < 2) A4 = cvt8v(x + (size_t)rm * NI + 8 * q);
        else { h8 z = {}; A4 = z; }

        f4v acc0 = {0.f,0.f,0.f,0.f}, acc1 = {0.f,0.f,0.f,0.f};
        f4v acc2 = {0.f,0.f,0.f,0.f}, acc3 = {0.f,0.f,0.f,0.f};
        acc0 = mfma16(A0, Bf[0][0], acc0); acc1 = mfma16(A0, Bf[1][0], acc1);
        acc2 = mfma16(A0, Bf[2][0], acc2); acc3 = mfma16(A0, Bf[3][0], acc3);
        acc0 = mfma16(A1, Bf[0][1], acc0); acc1 = mfma16(A1, Bf[1][1], acc1);
        acc2 = mfma16(A1, Bf[2][1], acc2); acc3 = mfma16(A1, Bf[3][1], acc3);
        acc0 = mfma16(A2, Bf[0][2], acc0); acc1 = mfma16(A2, Bf[1][2], acc1);
        acc2 = mfma16(A2, Bf[2][2], acc2); acc3 = mfma16(A2, Bf[3][2], acc3);
        acc0 = mfma16(A3, Bf[0][3], acc0); acc1 = mfma16(A3, Bf[1][3], acc1);
        acc2 = mfma16(A3, Bf[2][3], acc2); acc3 = mfma16(A3, Bf[3][3], acc3);
        acc0 = mfma16(A4, Bf[0][4], acc0); acc1 = mfma16(A4, Bf[1][4], acc1);
        acc2 = mfma16(A4, Bf[2][4], acc2); acc3 = mfma16(A4, Bf[3][4], acc3);

        float rs[4];
#pragma unroll
        for (int r = 0; r < 4; r++) {
            rs[r] = fmaxf(acc0[r] + b1v[0], 0.f) * w2v[0]
                  + fmaxf(acc1[r] + b1v[1], 0.f) * w2v[1]
                  + fmaxf(acc2[r] + b1v[2], 0.f) * w2v[2]
                  + fmaxf(acc3[r] + b1v[3], 0.f) * w2v[3];
        }
#pragma unroll
        for (int off = 1; off < 16; off <<= 1) {
#pragma unroll
            for (int r = 0; r < 4; r++)
                rs[r] += __shfl_xor(rs[r], off, 64);
        }
        if (nl == 0) {
            float4 o;
            o.x = tanh_fast(rs[0] + b2v) * 0.125f;
            o.y = tanh_fast(rs[1] + b2v) * 0.125f;
            o.z = tanh_fast(rs[2] + b2v) * 0.125f;
            o.w = tanh_fast(rs[3] + b2v) * 0.125f;
            *(float4*)(inc + row0 + 4 * q) = o;
        }
    }
}

// ---------------------------------------------------------------------------
// Inclusive cumsum over S per batch + initial offset. One block per batch.
// ---------------------------------------------------------------------------
__global__ __launch_bounds__(256)
void cumsum_kernel(const float* __restrict__ inc, const float* __restrict__ init,
                   float* __restrict__ out)
{
    __shared__ float sW[4];
    const int b = blockIdx.x;
    const int tid = threadIdx.x;
    const int lane = tid & 63;
    const int wid = tid >> 6;

    const float* ib = inc + (size_t)b * S;
    float v[16];
#pragma unroll
    for (int i = 0; i < 16; i++) v[i] = ib[tid * 16 + i];

    float run = 0.f;
#pragma unroll
    for (int i = 0; i < 16; i++) { run += v[i]; v[i] = run; }

    float t = run;
#pragma unroll
    for (int off = 1; off < 64; off <<= 1) {
        float u = __shfl_up(t, off, 64);
        if (lane >= off) t += u;
    }
    const float excl = t - run;
    if (lane == 63) sW[wid] = t;
    __syncthreads();

    float wo = 0.f;
#pragma unroll
    for (int w = 0; w < 4; w++) if (w < wid) wo += sW[w];

    const float prefix = wo + excl + init[0];
    float* ob = out + (size_t)b * S;
#pragma unroll
    for (int i = 0; i < 16; i++) ob[tid * 16 + i] = prefix + v[i];
}

// ---------------------------------------------------------------------------
extern "C" void kernel_launch(void* const* d_in, const int* in_sizes, int n_in,
                              void* d_out, int out_size, void* d_ws, size_t ws_size,
                              hipStream_t stream)
{
    const float* x     = (const float*)d_in[0];
    const float* w_ih0 = (const float*)d_in[1];
    const float* w_hh0 = (const float*)d_in[2];
    const float* b_ih0 = (const float*)d_in[3];
    const float* b_hh0 = (const float*)d_in[4];
    const float* w_ih1 = (const float*)d_in[5];
    const float* w_hh1 = (const float*)d_in[6];
    const float* b_ih1 = (const float*)d_in[7];
    const float* b_hh1 = (const float*)d_in[8];
    const float* w1    = (const float*)d_in[9];
    const float* b1    = (const float*)d_in[10];
    const float* w2    = (const float*)d_in[11];
    const float* b2    = (const float*)d_in[12];
    const float* init  = (const float*)d_in[13];
    float* out = (float*)d_out;

    _Float16* hbuf = (_Float16*)d_ws;                               // 67 MB fp16
    float* incbuf  = (float*)((char*)d_ws + (size_t)B * S * H * 2); // 1 MB

    hipLaunchKernelGGL(gru_fused, dim3(B), dim3(768), 0, stream,
                       x, w_ih0, w_hh0, b_ih0, b_hh0,
                       w_ih1, w_hh1, b_ih1, b_hh1, hbuf);
    hipLaunchKernelGGL(head_mfma, dim3(512), dim3(256), 0, stream,
                       hbuf, x, w1, b1, w2, b2, incbuf);
    hipLaunchKernelGGL(cumsum_kernel, dim3(B), dim3(256), 0, stream,
                       incbuf, init, out);
}